// Round 7
// baseline (53.529 us; speedup 1.0000x reference)
//
#include <hip/hip_runtime.h>

#define LSTREAM 512
#define C 8
#define OUTD 584    // 8 + 64 + 512
#define NW 16       // waves per block (segments per batch)
#define SEG 32      // steps per wave (wave 15's last step is an arithmetic no-op)
#define PSTRIDE 600 // partial-signature stride in floats

typedef __attribute__((ext_vector_type(8))) float f32x8;

// Wave-uniform row -> SGPRs on the scalar pipe. Waits are tied to the value
// ("+s") so dependent VALU cannot be hoisted above the wait.
#define SLOAD(dst, ptr) asm volatile("s_load_dwordx8 %0, %1, 0x0" : "=&s"(dst) : "s"(ptr))
#define SWAIT(x)        asm volatile("s_waitcnt lgkmcnt(0)" : "+s"(x))

// Chen combine: state (a, in regs) <- a (x) b (in LDS at bp). a is earlier.
// Lane = i*8+j owns a2[i][j] (s2), a3[i][j][0..7] (s3); s1i = a1[i].
__device__ __forceinline__ void chen_combine(const float* bp, int i, int j, int lane,
                                             float& s1i, float& s2, float (&s3)[C]) {
    const float  b1i  = bp[i];
    const float  b1j  = bp[j];
    const float4 b1lo = *reinterpret_cast<const float4*>(bp);
    const float4 b1hi = *reinterpret_cast<const float4*>(bp + 4);
    const float4 b2lo = *reinterpret_cast<const float4*>(bp + C + j * C);
    const float4 b2hi = *reinterpret_cast<const float4*>(bp + C + j * C + 4);
    const float  b2ij = bp[C + lane];
    const float4 b3lo = *reinterpret_cast<const float4*>(bp + C + 64 + lane * C);
    const float4 b3hi = *reinterpret_cast<const float4*>(bp + C + 64 + lane * C + 4);
    const float b1k[C]  = {b1lo.x, b1lo.y, b1lo.z, b1lo.w, b1hi.x, b1hi.y, b1hi.z, b1hi.w};
    const float b2jk[C] = {b2lo.x, b2lo.y, b2lo.z, b2lo.w, b2hi.x, b2hi.y, b2hi.z, b2hi.w};
    const float b3k[C]  = {b3lo.x, b3lo.y, b3lo.z, b3lo.w, b3hi.x, b3hi.y, b3hi.z, b3hi.w};
    #pragma unroll
    for (int k = 0; k < C; ++k)
        s3[k] = s3[k] + b3k[k] + s1i * b2jk[k] + s2 * b1k[k];
    s2 = s2 + b2ij + s1i * b1j;
    s1i += b1i;
}

__device__ __forceinline__ void store_partial(float* pp, int i, int j, int lane,
                                              float s1i, float s2, const float (&s3)[C]) {
    if (j == 0) pp[i] = s1i;
    pp[C + lane] = s2;
    #pragma unroll
    for (int k = 0; k < C; ++k) pp[C + 64 + lane * C + k] = s3[k];
}

__global__ __launch_bounds__(1024, 8) void sig_kernel(const float* __restrict__ path,
                                                      float* __restrict__ out) {
    __shared__ float part[NW * PSTRIDE];   // 37.5 KB: per-wave partial signatures
    const int b    = blockIdx.x;
    const int tid  = threadIdx.x;
    const int wu   = __builtin_amdgcn_readfirstlane(tid >> 6);  // uniform wave id (SGPR)
    const int lane = tid & 63;
    const int i = lane >> 3;
    const int j = lane & 7;

    const float* pb = path + (size_t)b * (LSTREAM * C);
    const int r0 = wu * SEG;

    // scalar-pipe row pipeline: rowNew = row r0 (waited), rowPre = row r0+1 (in flight)
    f32x8 rowNew, rowPre;
    SLOAD(rowNew, pb + (size_t)r0 * C);
    SWAIT(rowNew);
    SLOAD(rowPre, pb + (size_t)(r0 + 1) * C);

    // per-lane running path values (VMEM / vmcnt — disjoint from lgkm)
    float pi_prev = pb[r0 * C + i];
    float pj_prev = pb[r0 * C + j];

    float s1i = 0.f, s2 = 0.f;
    f32x8 F = {0.f, 0.f, 0.f, 0.f, 0.f, 0.f, 0.f, 0.f};  // sum coeff_t * row_{t+1}
    f32x8 G = {0.f, 0.f, 0.f, 0.f, 0.f, 0.f, 0.f, 0.f};  // sum coeff_t * row_t

    #pragma unroll
    for (int s = 0; s < SEG; ++s) {
        SWAIT(rowPre);
        const f32x8 rowOld = rowNew;   // row r0+s
        rowNew = rowPre;               // row r0+s+1
        const int rNxt = min(r0 + s + 2, LSTREAM - 1);  // clamp: phantom step is a no-op
        SLOAD(rowPre, pb + (size_t)rNxt * C);

        const int rCur = min(r0 + s + 1, LSTREAM - 1);
        const float pi_c = pb[rCur * C + i];
        const float pj_c = pb[rCur * C + j];
        const float dxi = pi_c - pi_prev; pi_prev = pi_c;
        const float dxj = pj_c - pj_prev; pj_prev = pj_c;

        const float u  = dxi * dxj;
        const float t1 = s1i * dxj;
        const float coeff = fmaf(u, (1.f / 6.f), fmaf(t1, 0.5f, s2));
        #pragma unroll
        for (int k = 0; k < C; ++k) F[k] = fmaf(coeff, rowNew[k], F[k]);
        #pragma unroll
        for (int k = 0; k < C; ++k) G[k] = fmaf(coeff, rowOld[k], G[k]);
        s2 = fmaf(u, 0.5f, s2) + t1;
        s1i += dxi;
    }
    SWAIT(rowPre);  // drain the final in-flight scalar load

    // s3[k] = sum coeff_t * (row_{t+1}[k] - row_t[k]) = F - G
    float s3[C];
    #pragma unroll
    for (int k = 0; k < C; ++k) s3[k] = F[k] - G[k];

    // ---- publish partials, tree-combine 16 -> 1 ----
    store_partial(part + wu * PSTRIDE, i, j, lane, s1i, s2, s3);
    __syncthreads();

    if ((wu & 1) == 0) chen_combine(part + (wu + 1) * PSTRIDE, i, j, lane, s1i, s2, s3);
    if (wu == 2 || wu == 6 || wu == 10 || wu == 14)
        store_partial(part + wu * PSTRIDE, i, j, lane, s1i, s2, s3);
    __syncthreads();

    if ((wu & 3) == 0) chen_combine(part + (wu + 2) * PSTRIDE, i, j, lane, s1i, s2, s3);
    if (wu == 4 || wu == 12)
        store_partial(part + wu * PSTRIDE, i, j, lane, s1i, s2, s3);
    __syncthreads();

    if ((wu & 7) == 0) chen_combine(part + (wu + 4) * PSTRIDE, i, j, lane, s1i, s2, s3);
    if (wu == 8)
        store_partial(part + wu * PSTRIDE, i, j, lane, s1i, s2, s3);
    __syncthreads();

    if (wu == 0) {
        chen_combine(part + 8 * PSTRIDE, i, j, lane, s1i, s2, s3);
        float* ob = out + (size_t)b * OUTD;
        const float s1out = __shfl(s1i, (lane << 3) & 63, 64);
        if (lane < C) ob[lane] = s1out;
        ob[C + lane] = s2;
        #pragma unroll
        for (int k = 0; k < C; ++k) ob[C + 64 + lane * C + k] = s3[k];
    }
}

extern "C" void kernel_launch(void* const* d_in, const int* in_sizes, int n_in,
                              void* d_out, int out_size, void* d_ws, size_t ws_size,
                              hipStream_t stream) {
    const float* path = (const float*)d_in[0];
    float* out = (float*)d_out;
    const int B = in_sizes[0] / (LSTREAM * C);
    sig_kernel<<<B, 1024, 0, stream>>>(path, out);
}

// Round 8
// 14.468 us; speedup vs baseline: 3.6999x; 3.6999x over previous
//
#include <hip/hip_runtime.h>

#define LSTREAM 512
#define C 8
#define OUTD 584    // 8 + 64 + 512
#define NW 16       // waves per block (segments per batch)
#define SEG 32      // steps per wave (wave 15's step 511 is an exact no-op)
#define INCF 4096   // 512 rows x 8 floats (row 511 zeroed)
#define PSTRIDE 600 // partial-signature stride in floats

typedef __attribute__((ext_vector_type(8))) float f32x8;

// Wave-uniform path row -> SGPRs on the scalar pipe. Wait is value-tied so
// row-consuming FMAs cannot be hoisted above it.
#define SLOAD(dst, ptr) asm volatile("s_load_dwordx8 %0, %1, 0x0" : "=&s"(dst) : "s"(ptr))
#define SWAIT(x)        asm volatile("s_waitcnt lgkmcnt(0)" : "+s"(x))

// Chen combine: state (a, in regs) <- a (x) b (in LDS at bp). a is earlier.
// Lane = i*8+j owns a2[i][j] (s2), a3[i][j][0..7] (s3); s1i = a1[i].
__device__ __forceinline__ void chen_combine(const float* bp, int i, int j, int lane,
                                             float& s1i, float& s2, float (&s3)[C]) {
    const float  b1i  = bp[i];
    const float  b1j  = bp[j];
    const float4 b1lo = *reinterpret_cast<const float4*>(bp);
    const float4 b1hi = *reinterpret_cast<const float4*>(bp + 4);
    const float4 b2lo = *reinterpret_cast<const float4*>(bp + C + j * C);
    const float4 b2hi = *reinterpret_cast<const float4*>(bp + C + j * C + 4);
    const float  b2ij = bp[C + lane];
    const float4 b3lo = *reinterpret_cast<const float4*>(bp + C + 64 + lane * C);
    const float4 b3hi = *reinterpret_cast<const float4*>(bp + C + 64 + lane * C + 4);
    const float b1k[C]  = {b1lo.x, b1lo.y, b1lo.z, b1lo.w, b1hi.x, b1hi.y, b1hi.z, b1hi.w};
    const float b2jk[C] = {b2lo.x, b2lo.y, b2lo.z, b2lo.w, b2hi.x, b2hi.y, b2hi.z, b2hi.w};
    const float b3k[C]  = {b3lo.x, b3lo.y, b3lo.z, b3lo.w, b3hi.x, b3hi.y, b3hi.z, b3hi.w};
    #pragma unroll
    for (int k = 0; k < C; ++k)
        s3[k] = s3[k] + b3k[k] + s1i * b2jk[k] + s2 * b1k[k];
    s2 = s2 + b2ij + s1i * b1j;
    s1i += b1i;
}

__device__ __forceinline__ void store_partial(float* pp, int i, int j, int lane,
                                              float s1i, float s2, const float (&s3)[C]) {
    if (j == 0) pp[i] = s1i;
    pp[C + lane] = s2;
    #pragma unroll
    for (int k = 0; k < C; ++k) pp[C + 64 + lane * C + k] = s3[k];
}

__global__ __launch_bounds__(1024, 8) void sig_kernel(const float* __restrict__ path,
                                                      float* __restrict__ out) {
    __shared__ float inc[INCF];            // 16 KB: increments, row 511 = 0
    __shared__ float part[NW * PSTRIDE];   // 37.5 KB: per-wave partials
    const int b    = blockIdx.x;
    const int tid  = threadIdx.x;
    const int wu   = __builtin_amdgcn_readfirstlane(tid >> 6);  // uniform wave id
    const int lane = tid & 63;
    const int i = lane >> 3;
    const int j = lane & 7;

    const float* pb = path + (size_t)b * (LSTREAM * C);

    // ---- pre-pass: increments -> LDS (coalesced float4); zero row 511 ----
    {
        const int row = tid >> 1;
        float4 d = {0.f, 0.f, 0.f, 0.f};
        if (row < LSTREAM - 1) {
            const float4* p4 = reinterpret_cast<const float4*>(pb);
            const float4 a = p4[tid];
            const float4 c = p4[tid + 2];
            d.x = c.x - a.x; d.y = c.y - a.y; d.z = c.z - a.z; d.w = c.w - a.w;
        }
        reinterpret_cast<float4*>(inc)[tid] = d;
    }
    __syncthreads();

    const int r0 = wu * SEG;
    const float* pI = inc + r0 * C + i;    // per-lane dxi stream (8-way broadcast, conflict-free)
    const float* pJ = inc + r0 * C + j;

    float s1i = 0.f, s2 = 0.f, coeff_prev = 0.f;
    float s3[C];
    #pragma unroll
    for (int k = 0; k < C; ++k) s3[k] = 0.f;

    // scalar row double-buffer: A = row r0+2m, B = row r0+2m+1
    f32x8 A, B;
    SLOAD(A, pb + ((size_t)r0 << 3));
    SLOAD(B, pb + ((size_t)(r0 + 1) << 3));

    // summation by parts: s3 = sum_r (coeff_{r-1} - coeff_r) * x_r + coeff_last * x_end
    #pragma unroll 4
    for (int m = 0; m < SEG / 2; ++m) {
        const int t0 = 2 * m;              // segment-local step index (row r0+t0)
        SWAIT(A); SWAIT(B);

        // ---- step t0 (uses row A = x[r0+t0]) ----
        {
            const float dxi = pI[t0 * C];
            const float dxj = pJ[t0 * C];
            const float u  = dxi * dxj;
            const float t1 = s1i * dxj;
            const float cf = fmaf(u, (1.f / 6.f), fmaf(t1, 0.5f, s2));
            const float w  = coeff_prev - cf;
            #pragma unroll
            for (int k = 0; k < C; ++k) s3[k] = fmaf(w, A[k], s3[k]);
            s2 = fmaf(u, 0.5f, s2) + t1;
            s1i += dxi;
            coeff_prev = cf;
        }
        {   // refill A with row r0+t0+2 (clamped; uniform SALU min)
            const int rn = min(r0 + t0 + 2, LSTREAM - 1);
            SLOAD(A, pb + ((size_t)rn << 3));
        }

        // ---- step t0+1 (uses row B = x[r0+t0+1]) ----
        {
            const float dxi = pI[(t0 + 1) * C];
            const float dxj = pJ[(t0 + 1) * C];
            const float u  = dxi * dxj;
            const float t1 = s1i * dxj;
            const float cf = fmaf(u, (1.f / 6.f), fmaf(t1, 0.5f, s2));
            const float w  = coeff_prev - cf;
            #pragma unroll
            for (int k = 0; k < C; ++k) s3[k] = fmaf(w, B[k], s3[k]);
            s2 = fmaf(u, 0.5f, s2) + t1;
            s1i += dxi;
            coeff_prev = cf;
        }
        {   // refill B with row r0+t0+3 (clamped)
            const int rn = min(r0 + t0 + 3, LSTREAM - 1);
            SLOAD(B, pb + ((size_t)rn << 3));
        }
    }
    SWAIT(A); SWAIT(B);
    // closing term: + coeff_last * x[min(r0+32, 511)] (held in A)
    #pragma unroll
    for (int k = 0; k < C; ++k) s3[k] = fmaf(coeff_prev, A[k], s3[k]);

    // ---- publish partials, tree-combine 16 -> 1 ----
    store_partial(part + wu * PSTRIDE, i, j, lane, s1i, s2, s3);
    __syncthreads();

    if ((wu & 1) == 0) chen_combine(part + (wu + 1) * PSTRIDE, i, j, lane, s1i, s2, s3);
    if (wu == 2 || wu == 6 || wu == 10 || wu == 14)
        store_partial(part + wu * PSTRIDE, i, j, lane, s1i, s2, s3);
    __syncthreads();

    if ((wu & 3) == 0) chen_combine(part + (wu + 2) * PSTRIDE, i, j, lane, s1i, s2, s3);
    if (wu == 4 || wu == 12)
        store_partial(part + wu * PSTRIDE, i, j, lane, s1i, s2, s3);
    __syncthreads();

    if ((wu & 7) == 0) chen_combine(part + (wu + 4) * PSTRIDE, i, j, lane, s1i, s2, s3);
    if (wu == 8)
        store_partial(part + wu * PSTRIDE, i, j, lane, s1i, s2, s3);
    __syncthreads();

    if (wu == 0) {
        chen_combine(part + 8 * PSTRIDE, i, j, lane, s1i, s2, s3);
        float* ob = out + (size_t)b * OUTD;
        const float s1out = __shfl(s1i, (lane << 3) & 63, 64);
        if (lane < C) ob[lane] = s1out;
        ob[C + lane] = s2;
        #pragma unroll
        for (int k = 0; k < C; ++k) ob[C + 64 + lane * C + k] = s3[k];
    }
}

extern "C" void kernel_launch(void* const* d_in, const int* in_sizes, int n_in,
                              void* d_out, int out_size, void* d_ws, size_t ws_size,
                              hipStream_t stream) {
    const float* path = (const float*)d_in[0];
    float* out = (float*)d_out;
    const int B = in_sizes[0] / (LSTREAM * C);
    sig_kernel<<<B, 1024, 0, stream>>>(path, out);
}